// Round 1
// baseline (1448.241 us; speedup 1.0000x reference)
//
#include <hip/hip_runtime.h>
#include <stddef.h>

#define E_EDGES   800000
#define N_NODES   25000
#define NRADIAL   6
#define HIDDEN    256
#define OUT_EMB   256
#define NUM_LAYERS 3

// ---------------------------------------------------------------------------
// CSR build: count -> scan -> fill
// ---------------------------------------------------------------------------
__global__ void count_kernel(const int* __restrict__ idx, int* __restrict__ cnt) {
    int e = blockIdx.x * blockDim.x + threadIdx.x;
    if (e < E_EDGES) atomicAdd(&cnt[idx[e]], 1);
}

// one block, 1024 threads; each thread scans 25 contiguous counters
__global__ __launch_bounds__(1024) void scan_kernel(const int* __restrict__ cnt,
                                                    int* __restrict__ off,
                                                    int* __restrict__ cur) {
    __shared__ int warpsum[16];
    const int PER = 25;                       // 1024*25 = 25600 >= 25000
    int t = threadIdx.x;
    int base = t * PER;
    int local[PER];
    int s = 0;
    #pragma unroll
    for (int j = 0; j < PER; ++j) {
        int n = base + j;
        int v = (n < N_NODES) ? cnt[n] : 0;
        local[j] = s;                         // exclusive within thread
        s += v;
    }
    int lane = t & 63, w = t >> 6;
    int incl = s;
    #pragma unroll
    for (int d = 1; d < 64; d <<= 1) {
        int y = __shfl_up(incl, d, 64);
        if (lane >= d) incl += y;
    }
    if (lane == 63) warpsum[w] = incl;
    __syncthreads();
    if (w == 0) {
        int v = (lane < 16) ? warpsum[lane] : 0;
        #pragma unroll
        for (int d = 1; d < 16; d <<= 1) {
            int y = __shfl_up(v, d, 64);
            if (lane >= d) v += y;
        }
        if (lane < 16) warpsum[lane] = v;     // inclusive per-wave
    }
    __syncthreads();
    int wbase = (w > 0) ? warpsum[w - 1] : 0;
    int texcl = wbase + (incl - s);           // exclusive prefix for this thread
    #pragma unroll
    for (int j = 0; j < PER; ++j) {
        int n = base + j;
        if (n < N_NODES) { int o = texcl + local[j]; off[n] = o; cur[n] = o; }
    }
}

__global__ void fill_kernel(const int* __restrict__ idx, int* __restrict__ cur,
                            int* __restrict__ elist) {
    int e = blockIdx.x * blockDim.x + threadIdx.x;
    if (e < E_EDGES) {
        int n = idx[e];
        int pos = atomicAdd(&cur[n], 1);
        elist[pos] = e;
    }
}

// ---------------------------------------------------------------------------
// Gather: one wave per node. lane owns 4 columns (float4).
// node_h[n][c] = sum_{e in node n} (sum_r rbf[e][r]*W_rbf[c][r]) * x[e][c]
// ---------------------------------------------------------------------------
__global__ __launch_bounds__(256) void gather_kernel(
        const float* __restrict__ x, const float* __restrict__ rbf,
        const float* __restrict__ W_rbf,
        const int* __restrict__ off, const int* __restrict__ cnt,
        const int* __restrict__ elist, float* __restrict__ node_h) {
    int wave = threadIdx.x >> 6;
    int lane = threadIdx.x & 63;
    int node = blockIdx.x * 4 + wave;
    if (node >= N_NODES) return;
    int c0 = lane * 4;

    float wr[4][NRADIAL];
    #pragma unroll
    for (int j = 0; j < 4; ++j)
        #pragma unroll
        for (int r = 0; r < NRADIAL; ++r)
            wr[j][r] = W_rbf[(c0 + j) * NRADIAL + r];

    float a0 = 0.f, a1 = 0.f, a2 = 0.f, a3 = 0.f;
    int start = off[node];
    int ne    = cnt[node];
    #pragma unroll 2
    for (int k = 0; k < ne; ++k) {
        int e = elist[start + k];
        const float2* r2 = reinterpret_cast<const float2*>(rbf + (size_t)e * NRADIAL);
        float2 ra = r2[0], rb = r2[1], rc = r2[2];
        float r0 = ra.x, r1 = ra.y, r2v = rb.x, r3 = rb.y, r4 = rc.x, r5 = rc.y;
        float4 xv = *reinterpret_cast<const float4*>(x + (size_t)e * HIDDEN + c0);
        float s0 = wr[0][0]*r0 + wr[0][1]*r1 + wr[0][2]*r2v + wr[0][3]*r3 + wr[0][4]*r4 + wr[0][5]*r5;
        float s1 = wr[1][0]*r0 + wr[1][1]*r1 + wr[1][2]*r2v + wr[1][3]*r3 + wr[1][4]*r4 + wr[1][5]*r5;
        float s2 = wr[2][0]*r0 + wr[2][1]*r1 + wr[2][2]*r2v + wr[2][3]*r3 + wr[2][4]*r4 + wr[2][5]*r5;
        float s3 = wr[3][0]*r0 + wr[3][1]*r1 + wr[3][2]*r2v + wr[3][3]*r3 + wr[3][4]*r4 + wr[3][5]*r5;
        a0 += s0 * xv.x; a1 += s1 * xv.y; a2 += s2 * xv.z; a3 += s3 * xv.w;
    }
    float4 o = make_float4(a0, a1, a2, a3);
    *reinterpret_cast<float4*>(node_h + (size_t)node * HIDDEN + c0) = o;
}

// ---------------------------------------------------------------------------
// fp32 SGEMM: C[M,BN-tile] = A[M,K] * W[N,K]^T (+bias, optional silu)
// BM=128, BN=64, BK=16, 256 threads, micro-tile 8x4 (M split 2x4)
// ---------------------------------------------------------------------------
template<int DO_SILU>
__global__ __launch_bounds__(256) void gemm_kernel(
        const float* __restrict__ A,      // [M, 256]
        const float* __restrict__ W,      // [256, 256] (out-major, K contiguous)
        const float* __restrict__ bias,   // [256]
        float* __restrict__ C,            // [M, 256]
        int M) {
    constexpr int K  = 256;
    constexpr int BM = 128, BN = 64, BK = 16;
    __shared__ float As[BK][BM];
    __shared__ float Wsh[BK][BN];

    int tid  = threadIdx.x;
    int row0 = blockIdx.x * BM;
    int col0 = blockIdx.y * BN;
    int tx = tid & 15;            // 16 col groups
    int ty = tid >> 4;            // 16 row groups
    int tn  = tx * 4;             // 4 cols
    int tm1 = ty * 4;             // rows split: ty*4 and 64+ty*4
    int tm2 = 64 + ty * 4;

    float acc[2][4][4];
    #pragma unroll
    for (int mi = 0; mi < 2; ++mi)
        #pragma unroll
        for (int i = 0; i < 4; ++i)
            #pragma unroll
            for (int j = 0; j < 4; ++j) acc[mi][i][j] = 0.f;

    for (int kc = 0; kc < K; kc += BK) {
        // stage A: 128x16 floats = 512 float4, 2 per thread
        #pragma unroll
        for (int l = 0; l < 2; ++l) {
            int id = tid * 2 + l;
            int r  = id >> 2;
            int kq = (id & 3) * 4;
            int grow = row0 + r;
            float4 v = make_float4(0.f, 0.f, 0.f, 0.f);
            if (grow < M)
                v = *reinterpret_cast<const float4*>(A + (size_t)grow * K + kc + kq);
            As[kq + 0][r] = v.x; As[kq + 1][r] = v.y;
            As[kq + 2][r] = v.z; As[kq + 3][r] = v.w;
        }
        // stage W: 64x16 floats = 256 float4, 1 per thread
        {
            int r  = tid >> 2;
            int kq = (tid & 3) * 4;
            float4 v = *reinterpret_cast<const float4*>(W + (size_t)(col0 + r) * K + kc + kq);
            Wsh[kq + 0][r] = v.x; Wsh[kq + 1][r] = v.y;
            Wsh[kq + 2][r] = v.z; Wsh[kq + 3][r] = v.w;
        }
        __syncthreads();
        #pragma unroll
        for (int k = 0; k < BK; ++k) {
            float4 av1 = *reinterpret_cast<const float4*>(&As[k][tm1]);
            float4 av2 = *reinterpret_cast<const float4*>(&As[k][tm2]);
            float4 wv  = *reinterpret_cast<const float4*>(&Wsh[k][tn]);
            float a1v[4] = {av1.x, av1.y, av1.z, av1.w};
            float a2v[4] = {av2.x, av2.y, av2.z, av2.w};
            float wvv[4] = {wv.x, wv.y, wv.z, wv.w};
            #pragma unroll
            for (int i = 0; i < 4; ++i)
                #pragma unroll
                for (int j = 0; j < 4; ++j) {
                    acc[0][i][j] += a1v[i] * wvv[j];
                    acc[1][i][j] += a2v[i] * wvv[j];
                }
        }
        __syncthreads();
    }

    float4 bv = *reinterpret_cast<const float4*>(bias + col0 + tn);
    float bvv[4] = {bv.x, bv.y, bv.z, bv.w};
    #pragma unroll
    for (int mi = 0; mi < 2; ++mi) {
        int rbase = row0 + (mi ? tm2 : tm1);
        #pragma unroll
        for (int i = 0; i < 4; ++i) {
            int grow = rbase + i;
            if (grow < M) {
                float o[4];
                #pragma unroll
                for (int j = 0; j < 4; ++j) {
                    float v = acc[mi][i][j] + bvv[j];
                    if (DO_SILU) v = v / (1.f + expf(-v));
                    o[j] = v;
                }
                *reinterpret_cast<float4*>(C + (size_t)grow * 256 + col0 + tn) =
                    make_float4(o[0], o[1], o[2], o[3]);
            }
        }
    }
}

// ---------------------------------------------------------------------------
// Final: out[n] = sum_o H[n][o] * W_out[o]   (one wave per row)
// ---------------------------------------------------------------------------
__global__ __launch_bounds__(256) void final_kernel(const float* __restrict__ H,
                                                    const float* __restrict__ Wout,
                                                    float* __restrict__ out, int M) {
    int wave = threadIdx.x >> 6, lane = threadIdx.x & 63;
    int row = blockIdx.x * 4 + wave;
    if (row >= M) return;
    float4 w = *reinterpret_cast<const float4*>(Wout + lane * 4);
    float4 h = *reinterpret_cast<const float4*>(H + (size_t)row * 256 + lane * 4);
    float s = h.x * w.x + h.y * w.y + h.z * w.z + h.w * w.w;
    #pragma unroll
    for (int d = 32; d > 0; d >>= 1) s += __shfl_down(s, d, 64);
    if (lane == 0) out[row] = s;
}

// ---------------------------------------------------------------------------
extern "C" void kernel_launch(void* const* d_in, const int* in_sizes, int n_in,
                              void* d_out, int out_size, void* d_ws, size_t ws_size,
                              hipStream_t stream) {
    const float* x     = (const float*)d_in[0];
    const float* rbf   = (const float*)d_in[1];
    const int*   idx   = (const int*)d_in[2];
    // d_in[3] = num_nodes scalar (hardcoded 25000)
    const float* W_rbf = (const float*)d_in[4];
    const float* W_up  = (const float*)d_in[5];
    const float* b_up  = (const float*)d_in[6];
    const float* Wl    = (const float*)d_in[7];   // [3][256][256]
    const float* bl    = (const float*)d_in[8];   // [3][256]
    const float* W_out = (const float*)d_in[9];   // [1][256]
    float* out = (float*)d_out;

    char* ws = (char*)d_ws;
    const size_t SZ_CNT = 102400;                    // 25000*4 rounded up
    const size_t SZ_EL  = (size_t)E_EDGES * 4;       // 3.2 MB
    const size_t SZ_ACT = (size_t)N_NODES * 256 * 4; // 25.6 MB
    int*   cnt    = (int*)(ws);
    int*   off    = (int*)(ws + SZ_CNT);
    int*   cur    = (int*)(ws + 2 * SZ_CNT);
    int*   elist  = (int*)(ws + 3 * SZ_CNT);
    float* node_h = (float*)(ws + 3 * SZ_CNT + SZ_EL);
    float* bufA   = (float*)(ws + 3 * SZ_CNT + SZ_EL + SZ_ACT);
    float* bufB   = (float*)(ws + 3 * SZ_CNT + SZ_EL + 2 * SZ_ACT);

    hipMemsetAsync(cnt, 0, N_NODES * sizeof(int), stream);
    count_kernel<<<(E_EDGES + 255) / 256, 256, 0, stream>>>(idx, cnt);
    scan_kernel<<<1, 1024, 0, stream>>>(cnt, off, cur);
    fill_kernel<<<(E_EDGES + 255) / 256, 256, 0, stream>>>(idx, cur, elist);
    gather_kernel<<<N_NODES / 4, 256, 0, stream>>>(x, rbf, W_rbf, off, cnt, elist, node_h);

    dim3 gg((N_NODES + 127) / 128, 256 / 64);
    gemm_kernel<0><<<gg, 256, 0, stream>>>(node_h, W_up, b_up, bufA, N_NODES);
    gemm_kernel<1><<<gg, 256, 0, stream>>>(bufA, Wl + 0 * 65536, bl + 0,   bufB, N_NODES);
    gemm_kernel<1><<<gg, 256, 0, stream>>>(bufB, Wl + 1 * 65536, bl + 256, bufA, N_NODES);
    gemm_kernel<1><<<gg, 256, 0, stream>>>(bufA, Wl + 2 * 65536, bl + 512, bufB, N_NODES);
    final_kernel<<<(N_NODES + 3) / 4, 256, 0, stream>>>(bufB, W_out, out, N_NODES);
}

// Round 2
// 1315.140 us; speedup vs baseline: 1.1012x; 1.1012x over previous
//
#include <hip/hip_runtime.h>
#include <stddef.h>
#include <stdint.h>

#define E_EDGES   800000
#define N_NODES   25000
#define MROWS_PAD 25088          // 196 * 128
#define NBLK_M    196

typedef __attribute__((ext_vector_type(8))) short frag8;   // 8 bf16 (4 VGPRs)
typedef __attribute__((ext_vector_type(4))) float f32x4;   // MFMA C/D

// ---------------- bf16 helpers (RNE) ----------------
__device__ __forceinline__ unsigned short f2b(float f) {
    union { float f; unsigned int u; } c; c.f = f;
    unsigned int u = c.u;
    return (unsigned short)((u + 0x7fffu + ((u >> 16) & 1u)) >> 16);
}
__device__ __forceinline__ float b2f(unsigned short h) {
    union { unsigned int u; float f; } c; c.u = ((unsigned int)h) << 16;
    return c.f;
}
__device__ __forceinline__ void split2(float v, unsigned short& hi, unsigned short& lo) {
    hi = f2b(v);
    lo = f2b(v - b2f(hi));   // exact residual (Sterbenz), then RNE
}

__device__ __forceinline__ void gl_lds16(const void* g, void* l) {
    __builtin_amdgcn_global_load_lds(
        (const __attribute__((address_space(1))) unsigned int*)g,
        (__attribute__((address_space(3))) unsigned int*)l, 16, 0, 0);
}

// ---------------------------------------------------------------------------
// CSR build: count -> scan -> fill
// ---------------------------------------------------------------------------
__global__ void count_kernel(const int* __restrict__ idx, int* __restrict__ cnt) {
    int e = blockIdx.x * blockDim.x + threadIdx.x;
    if (e < E_EDGES) atomicAdd(&cnt[idx[e]], 1);
}

__global__ __launch_bounds__(1024) void scan_kernel(const int* __restrict__ cnt,
                                                    int* __restrict__ off,
                                                    int* __restrict__ cur) {
    __shared__ int warpsum[16];
    const int PER = 25;
    int t = threadIdx.x;
    int base = t * PER;
    int local[PER];
    int s = 0;
    #pragma unroll
    for (int j = 0; j < PER; ++j) {
        int n = base + j;
        int v = (n < N_NODES) ? cnt[n] : 0;
        local[j] = s;
        s += v;
    }
    int lane = t & 63, w = t >> 6;
    int incl = s;
    #pragma unroll
    for (int d = 1; d < 64; d <<= 1) {
        int y = __shfl_up(incl, d, 64);
        if (lane >= d) incl += y;
    }
    if (lane == 63) warpsum[w] = incl;
    __syncthreads();
    if (w == 0) {
        int v = (lane < 16) ? warpsum[lane] : 0;
        #pragma unroll
        for (int d = 1; d < 16; d <<= 1) {
            int y = __shfl_up(v, d, 64);
            if (lane >= d) v += y;
        }
        if (lane < 16) warpsum[lane] = v;
    }
    __syncthreads();
    int wbase = (w > 0) ? warpsum[w - 1] : 0;
    int texcl = wbase + (incl - s);
    #pragma unroll
    for (int j = 0; j < PER; ++j) {
        int n = base + j;
        if (n < N_NODES) { int o = texcl + local[j]; off[n] = o; cur[n] = o; }
    }
}

__global__ void fill_kernel(const int* __restrict__ idx, int* __restrict__ cur,
                            int* __restrict__ elist) {
    int e = blockIdx.x * blockDim.x + threadIdx.x;
    if (e < E_EDGES) {
        int pos = atomicAdd(&cur[idx[e]], 1);
        elist[pos] = e;
    }
}

// ---------------------------------------------------------------------------
// Weight conversion: fp32 [256][256] -> bf16 hi|lo [256][512], 4 matrices
// matrix 0 = W_up, 1..3 = Ws[l]
// ---------------------------------------------------------------------------
__global__ void wconv_kernel(const float* __restrict__ Wup,
                             const float* __restrict__ Wl,
                             unsigned short* __restrict__ W2all) {
    int t = blockIdx.x * blockDim.x + threadIdx.x;
    if (t >= 4 * 65536) return;
    int m = t >> 16, rem = t & 65535;
    int o = rem >> 8, k = rem & 255;
    float v = (m == 0) ? Wup[rem] : Wl[(m - 1) * 65536 + rem];
    unsigned short hi, lo; split2(v, hi, lo);
    unsigned short* row = W2all + (size_t)m * 131072 + (size_t)o * 512;
    row[k] = hi; row[256 + k] = lo;
}

// ---------------------------------------------------------------------------
// Gather: one wave per node; lane owns 4 cols. Output bf16 hi|lo [row][512].
// ---------------------------------------------------------------------------
__global__ __launch_bounds__(256) void gather_kernel(
        const float* __restrict__ x, const float* __restrict__ rbf,
        const float* __restrict__ W_rbf,
        const int* __restrict__ off, const int* __restrict__ cnt,
        const int* __restrict__ elist, unsigned short* __restrict__ H2) {
    int wave = threadIdx.x >> 6;
    int lane = threadIdx.x & 63;
    int node = blockIdx.x * 4 + wave;
    if (node >= N_NODES) return;
    int c0 = lane * 4;

    float wr[4][6];
    #pragma unroll
    for (int j = 0; j < 4; ++j)
        #pragma unroll
        for (int r = 0; r < 6; ++r)
            wr[j][r] = W_rbf[(c0 + j) * 6 + r];

    float a0 = 0.f, a1 = 0.f, a2 = 0.f, a3 = 0.f;
    int start = off[node];
    int ne    = cnt[node];
    for (int base = 0; base < ne; base += 64) {
        int rem = ne - base;
        int nb  = rem < 64 ? rem : 64;
        int my_e = elist[start + base + (lane < rem ? lane : 0)];
        #pragma unroll 2
        for (int j = 0; j < nb; ++j) {
            int e = __shfl(my_e, j, 64);
            const float2* r2 = reinterpret_cast<const float2*>(rbf + (size_t)e * 6);
            float2 ra = r2[0], rb = r2[1], rc = r2[2];
            float4 xv = *reinterpret_cast<const float4*>(x + (size_t)e * 256 + c0);
            float s0 = wr[0][0]*ra.x + wr[0][1]*ra.y + wr[0][2]*rb.x + wr[0][3]*rb.y + wr[0][4]*rc.x + wr[0][5]*rc.y;
            float s1 = wr[1][0]*ra.x + wr[1][1]*ra.y + wr[1][2]*rb.x + wr[1][3]*rb.y + wr[1][4]*rc.x + wr[1][5]*rc.y;
            float s2 = wr[2][0]*ra.x + wr[2][1]*ra.y + wr[2][2]*rb.x + wr[2][3]*rb.y + wr[2][4]*rc.x + wr[2][5]*rc.y;
            float s3 = wr[3][0]*ra.x + wr[3][1]*ra.y + wr[3][2]*rb.x + wr[3][3]*rb.y + wr[3][4]*rc.x + wr[3][5]*rc.y;
            a0 += s0 * xv.x; a1 += s1 * xv.y; a2 += s2 * xv.z; a3 += s3 * xv.w;
        }
    }
    ushort4 hi4, lo4;
    split2(a0, hi4.x, lo4.x);
    split2(a1, hi4.y, lo4.y);
    split2(a2, hi4.z, lo4.z);
    split2(a3, hi4.w, lo4.w);
    *reinterpret_cast<ushort4*>(H2 + (size_t)node * 512 + c0)       = hi4;
    *reinterpret_cast<ushort4*>(H2 + (size_t)node * 512 + 256 + c0) = lo4;
}

// ---------------------------------------------------------------------------
// MFMA GEMM: C = silu?(A * W^T + b), A,W stored as bf16 hi|lo rows of 512.
// Computes Ahi*Whi + Ahi*Wlo + Alo*Whi via 12 K-stages of 64.
// BM=128, BN=256(all), 512 threads (8 waves, 2x4), 16x16x32 bf16 MFMA.
// LDS: 2 x (A 16KB + W 32KB) = 96KB, one barrier per stage.
// XOR swizzle on kc (both sides) to kill the stride-128B bank conflict.
// ---------------------------------------------------------------------------
template<int DO_SILU>
__global__ __launch_bounds__(512, 1) void gemm_mfma(
        const unsigned short* __restrict__ A2,   // [MROWS_PAD][512]
        const unsigned short* __restrict__ W2,   // [256][512]
        const float* __restrict__ bias,          // [256]
        unsigned short* __restrict__ C2,         // [MROWS_PAD][512]
        int M) {
    constexpr int NST = 12;
    __shared__ char lds[2][49152];               // [buf][A:0..16K | W:16K..48K]
    int tid  = threadIdx.x;
    int row0 = blockIdx.x * 128;
    int wid  = tid >> 6, lane = tid & 63;
    int wm   = (wid >> 2) * 64;                  // 0 / 64
    int wn   = (wid & 3) * 64;                   // 0 / 64 / 128 / 192
    int fr   = lane & 15, fq = lane >> 4;

    f32x4 acc[4][4];
    #pragma unroll
    for (int mi = 0; mi < 4; ++mi)
        #pragma unroll
        for (int nj = 0; nj < 4; ++nj)
            acc[mi][nj] = (f32x4){0.f, 0.f, 0.f, 0.f};

    auto stage = [&](int s, int b) {
        int part = s >> 2, q = (s & 3) * 64;
        int a_k0 = (part == 2 ? 256 : 0) + q;    // hi,hi,lo
        int w_k0 = (part == 1 ? 256 : 0) + q;    // hi,lo,hi
        #pragma unroll
        for (int l = 0; l < 2; ++l) {            // A: 1024 chunks of 16B
            int chunk = l * 512 + tid;
            int r = chunk >> 3, kc = chunk & 7;
            int kcs = kc ^ (r & 7);              // inverse-swizzled SOURCE
            gl_lds16(A2 + (size_t)(row0 + r) * 512 + a_k0 + kcs * 8,
                     &lds[b][chunk * 16]);
        }
        #pragma unroll
        for (int l = 0; l < 4; ++l) {            // W: 2048 chunks of 16B
            int chunk = l * 512 + tid;
            int r = chunk >> 3, kc = chunk & 7;
            int kcs = kc ^ (r & 7);
            gl_lds16(W2 + (size_t)r * 512 + w_k0 + kcs * 8,
                     &lds[b][16384 + chunk * 16]);
        }
    };

    stage(0, 0);
    __syncthreads();
    for (int s = 0; s < NST; ++s) {
        if (s + 1 < NST) stage(s + 1, (s + 1) & 1);
        const char* bufA = lds[s & 1];
        const char* bufW = lds[s & 1] + 16384;
        #pragma unroll
        for (int ks = 0; ks < 2; ++ks) {
            frag8 a[4], b[4];
            #pragma unroll
            for (int mi = 0; mi < 4; ++mi) {
                int r  = wm + mi * 16 + fr;
                int kc = ks * 4 + fq;
                int kcs = kc ^ (r & 7);          // swizzled READ
                a[mi] = *reinterpret_cast<const frag8*>(bufA + r * 128 + kcs * 16);
            }
            #pragma unroll
            for (int nj = 0; nj < 4; ++nj) {
                int r  = wn + nj * 16 + fr;
                int kc = ks * 4 + fq;
                int kcs = kc ^ (r & 7);
                b[nj] = *reinterpret_cast<const frag8*>(bufW + r * 128 + kcs * 16);
            }
            #pragma unroll
            for (int mi = 0; mi < 4; ++mi)
                #pragma unroll
                for (int nj = 0; nj < 4; ++nj)
                    acc[mi][nj] = __builtin_amdgcn_mfma_f32_16x16x32_bf16(
                        a[mi], b[nj], acc[mi][nj], 0, 0, 0);
        }
        __syncthreads();   // staged s+1 complete (vmcnt drain) + buf reuse safe
    }

    // epilogue: C/D map col=lane&15, row=(lane>>4)*4+reg  [m89-verified]
    #pragma unroll
    for (int mi = 0; mi < 4; ++mi) {
        #pragma unroll
        for (int r = 0; r < 4; ++r) {
            int grow = row0 + wm + mi * 16 + fq * 4 + r;
            if (grow < M) {
                #pragma unroll
                for (int nj = 0; nj < 4; ++nj) {
                    int col = wn + nj * 16 + fr;
                    float v = acc[mi][nj][r] + bias[col];
                    if (DO_SILU) v = v / (1.f + expf(-v));
                    unsigned short hi, lo; split2(v, hi, lo);
                    C2[(size_t)grow * 512 + col]       = hi;
                    C2[(size_t)grow * 512 + 256 + col] = lo;
                }
            }
        }
    }
}

// ---------------------------------------------------------------------------
// Final: out[n] = sum_o (hi+lo)(H[n][o]) * W_out[o]
// ---------------------------------------------------------------------------
__global__ __launch_bounds__(256) void final_kernel(const unsigned short* __restrict__ H2,
                                                    const float* __restrict__ Wout,
                                                    float* __restrict__ out, int M) {
    int wave = threadIdx.x >> 6, lane = threadIdx.x & 63;
    int row = blockIdx.x * 4 + wave;
    if (row >= M) return;
    float4 w = *reinterpret_cast<const float4*>(Wout + lane * 4);
    ushort4 h = *reinterpret_cast<const ushort4*>(H2 + (size_t)row * 512 + lane * 4);
    ushort4 l = *reinterpret_cast<const ushort4*>(H2 + (size_t)row * 512 + 256 + lane * 4);
    float s = (b2f(h.x) + b2f(l.x)) * w.x + (b2f(h.y) + b2f(l.y)) * w.y +
              (b2f(h.z) + b2f(l.z)) * w.z + (b2f(h.w) + b2f(l.w)) * w.w;
    #pragma unroll
    for (int d = 32; d > 0; d >>= 1) s += __shfl_down(s, d, 64);
    if (lane == 0) out[row] = s;
}

// ---------------------------------------------------------------------------
extern "C" void kernel_launch(void* const* d_in, const int* in_sizes, int n_in,
                              void* d_out, int out_size, void* d_ws, size_t ws_size,
                              hipStream_t stream) {
    const float* x     = (const float*)d_in[0];
    const float* rbf   = (const float*)d_in[1];
    const int*   idx   = (const int*)d_in[2];
    const float* W_rbf = (const float*)d_in[4];
    const float* W_up  = (const float*)d_in[5];
    const float* b_up  = (const float*)d_in[6];
    const float* Wl    = (const float*)d_in[7];
    const float* bl    = (const float*)d_in[8];
    const float* W_out = (const float*)d_in[9];
    float* out = (float*)d_out;

    char* ws = (char*)d_ws;
    int*            cnt   = (int*)(ws);
    int*            off   = (int*)(ws + 131072);
    int*            cur   = (int*)(ws + 262144);
    int*            elist = (int*)(ws + 393216);                    // 3.2 MB
    unsigned short* W2all = (unsigned short*)(ws + 3670016);        // 1 MB
    unsigned short* H2    = (unsigned short*)(ws + 4718592);        // 25.7 MB each
    unsigned short* bufA2 = (unsigned short*)(ws + 30408704);
    unsigned short* bufB2 = (unsigned short*)(ws + 56098816);

    hipMemsetAsync(cnt, 0, N_NODES * sizeof(int), stream);
    count_kernel<<<(E_EDGES + 255) / 256, 256, 0, stream>>>(idx, cnt);
    scan_kernel<<<1, 1024, 0, stream>>>(cnt, off, cur);
    fill_kernel<<<(E_EDGES + 255) / 256, 256, 0, stream>>>(idx, cur, elist);
    wconv_kernel<<<1024, 256, 0, stream>>>(W_up, Wl, W2all);
    gather_kernel<<<N_NODES / 4, 256, 0, stream>>>(x, rbf, W_rbf, off, cnt, elist, H2);

    gemm_mfma<0><<<NBLK_M, 512, 0, stream>>>(H2,    W2all + 0 * 131072, b_up,     bufA2, N_NODES);
    gemm_mfma<1><<<NBLK_M, 512, 0, stream>>>(bufA2, W2all + 1 * 131072, bl + 0,   bufB2, N_NODES);
    gemm_mfma<1><<<NBLK_M, 512, 0, stream>>>(bufB2, W2all + 2 * 131072, bl + 256, bufA2, N_NODES);
    gemm_mfma<1><<<NBLK_M, 512, 0, stream>>>(bufA2, W2all + 3 * 131072, bl + 512, bufB2, N_NODES);
    final_kernel<<<(N_NODES + 3) / 4, 256, 0, stream>>>(bufB2, W_out, out, N_NODES);
}

// Round 3
// 1296.441 us; speedup vs baseline: 1.1171x; 1.0144x over previous
//
#include <hip/hip_runtime.h>
#include <stddef.h>
#include <stdint.h>

#define E_EDGES   800000
#define N_NODES   25000
#define MROWS_PAD 25088          // 196 * 128
#define NBLK_M    196

typedef __attribute__((ext_vector_type(8))) short frag8;   // 8 bf16 (4 VGPRs)
typedef __attribute__((ext_vector_type(4))) float f32x4;   // MFMA C/D

// ---------------- bf16 helpers (RNE) ----------------
__device__ __forceinline__ unsigned short f2b(float f) {
    union { float f; unsigned int u; } c; c.f = f;
    unsigned int u = c.u;
    return (unsigned short)((u + 0x7fffu + ((u >> 16) & 1u)) >> 16);
}
__device__ __forceinline__ float b2f(unsigned short h) {
    union { unsigned int u; float f; } c; c.u = ((unsigned int)h) << 16;
    return c.f;
}
__device__ __forceinline__ void split2(float v, short& hi, short& lo) {
    unsigned short h = f2b(v);
    hi = (short)h;
    lo = (short)f2b(v - b2f(h));
}

__device__ __forceinline__ void gl_lds16(const void* g, void* l) {
    __builtin_amdgcn_global_load_lds(
        (const __attribute__((address_space(1))) unsigned int*)g,
        (__attribute__((address_space(3))) unsigned int*)l, 16, 0, 0);
}

// ---------------------------------------------------------------------------
// CSR build: count -> scan -> fill
// ---------------------------------------------------------------------------
__global__ void count_kernel(const int* __restrict__ idx, int* __restrict__ cnt) {
    int e = blockIdx.x * blockDim.x + threadIdx.x;
    if (e < E_EDGES) atomicAdd(&cnt[idx[e]], 1);
}

__global__ __launch_bounds__(1024) void scan_kernel(const int* __restrict__ cnt,
                                                    int* __restrict__ off,
                                                    int* __restrict__ cur) {
    __shared__ int warpsum[16];
    const int PER = 25;
    int t = threadIdx.x;
    int base = t * PER;
    int local[PER];
    int s = 0;
    #pragma unroll
    for (int j = 0; j < PER; ++j) {
        int n = base + j;
        int v = (n < N_NODES) ? cnt[n] : 0;
        local[j] = s;
        s += v;
    }
    int lane = t & 63, w = t >> 6;
    int incl = s;
    #pragma unroll
    for (int d = 1; d < 64; d <<= 1) {
        int y = __shfl_up(incl, d, 64);
        if (lane >= d) incl += y;
    }
    if (lane == 63) warpsum[w] = incl;
    __syncthreads();
    if (w == 0) {
        int v = (lane < 16) ? warpsum[lane] : 0;
        #pragma unroll
        for (int d = 1; d < 16; d <<= 1) {
            int y = __shfl_up(v, d, 64);
            if (lane >= d) v += y;
        }
        if (lane < 16) warpsum[lane] = v;
    }
    __syncthreads();
    int wbase = (w > 0) ? warpsum[w - 1] : 0;
    int texcl = wbase + (incl - s);
    #pragma unroll
    for (int j = 0; j < PER; ++j) {
        int n = base + j;
        if (n < N_NODES) { int o = texcl + local[j]; off[n] = o; cur[n] = o; }
    }
}

__global__ void fill_kernel(const int* __restrict__ idx, int* __restrict__ cur,
                            int* __restrict__ elist) {
    int e = blockIdx.x * blockDim.x + threadIdx.x;
    if (e < E_EDGES) {
        int pos = atomicAdd(&cur[idx[e]], 1);
        elist[pos] = e;
    }
}

// ---------------------------------------------------------------------------
// Weight conversion: fp32 [256][256] -> bf16 hi|lo [256][512], 4 matrices
// ---------------------------------------------------------------------------
__global__ void wconv_kernel(const float* __restrict__ Wup,
                             const float* __restrict__ Wl,
                             unsigned short* __restrict__ W2all) {
    int t = blockIdx.x * blockDim.x + threadIdx.x;
    if (t >= 4 * 65536) return;
    int m = t >> 16, rem = t & 65535;
    int o = rem >> 8, k = rem & 255;
    float v = (m == 0) ? Wup[rem] : Wl[(m - 1) * 65536 + rem];
    short hi, lo; split2(v, hi, lo);
    unsigned short* row = W2all + (size_t)m * 131072 + (size_t)o * 512;
    row[k] = (unsigned short)hi; row[256 + k] = (unsigned short)lo;
}

// ---------------------------------------------------------------------------
// Gather: ONE WAVE PER NODE (block=64). 4-deep x-row prefetch.
// node_h[n][c] = sum_{e in node n} (sum_r rbf[e][r]*W_rbf[c][r]) * x[e][c]
// ---------------------------------------------------------------------------
__global__ __launch_bounds__(64) void gather_kernel(
        const float* __restrict__ x, const float* __restrict__ rbf,
        const float* __restrict__ W_rbf,
        const int* __restrict__ off, const int* __restrict__ cnt,
        const int* __restrict__ elist, float* __restrict__ node_h) {
    int node = blockIdx.x;
    int lane = threadIdx.x;
    int c0 = lane * 4;
    float4 zero = make_float4(0.f, 0.f, 0.f, 0.f);
    if (node >= N_NODES) {           // zero pad rows so mlp_fused reads clean data
        *reinterpret_cast<float4*>(node_h + (size_t)node * 256 + c0) = zero;
        return;
    }
    float wr[4][6];
    #pragma unroll
    for (int j = 0; j < 4; ++j)
        #pragma unroll
        for (int r = 0; r < 6; ++r)
            wr[j][r] = W_rbf[(c0 + j) * 6 + r];

    float a0 = 0.f, a1 = 0.f, a2 = 0.f, a3 = 0.f;
    int start = off[node];
    int ne    = cnt[node];

    for (int base = 0; base < ne; base += 64) {
        int nb = ne - base; if (nb > 64) nb = 64;
        int my_e = elist[start + base + (lane < nb ? lane : nb - 1)];
        // lane's own rbf (broadcast later via shfl)
        const float* rp = rbf + (size_t)my_e * 6;
        float2 q0 = *reinterpret_cast<const float2*>(rp);
        float2 q1 = *reinterpret_cast<const float2*>(rp + 2);
        float2 q2 = *reinterpret_cast<const float2*>(rp + 4);

        auto edge = [&](int j, const float4& xv) {
            float r0 = __shfl(q0.x, j, 64), r1 = __shfl(q0.y, j, 64);
            float r2 = __shfl(q1.x, j, 64), r3 = __shfl(q1.y, j, 64);
            float r4 = __shfl(q2.x, j, 64), r5 = __shfl(q2.y, j, 64);
            float s0 = wr[0][0]*r0 + wr[0][1]*r1 + wr[0][2]*r2 + wr[0][3]*r3 + wr[0][4]*r4 + wr[0][5]*r5;
            float s1 = wr[1][0]*r0 + wr[1][1]*r1 + wr[1][2]*r2 + wr[1][3]*r3 + wr[1][4]*r4 + wr[1][5]*r5;
            float s2 = wr[2][0]*r0 + wr[2][1]*r1 + wr[2][2]*r2 + wr[2][3]*r3 + wr[2][4]*r4 + wr[2][5]*r5;
            float s3 = wr[3][0]*r0 + wr[3][1]*r1 + wr[3][2]*r2 + wr[3][3]*r3 + wr[3][4]*r4 + wr[3][5]*r5;
            a0 += s0 * xv.x; a1 += s1 * xv.y; a2 += s2 * xv.z; a3 += s3 * xv.w;
        };

        int jj = 0;
        for (; jj + 4 <= nb; jj += 4) {
            int e0 = __shfl(my_e, jj,     64);
            int e1 = __shfl(my_e, jj + 1, 64);
            int e2 = __shfl(my_e, jj + 2, 64);
            int e3 = __shfl(my_e, jj + 3, 64);
            float4 x0 = *reinterpret_cast<const float4*>(x + (size_t)e0 * 256 + c0);
            float4 x1 = *reinterpret_cast<const float4*>(x + (size_t)e1 * 256 + c0);
            float4 x2 = *reinterpret_cast<const float4*>(x + (size_t)e2 * 256 + c0);
            float4 x3 = *reinterpret_cast<const float4*>(x + (size_t)e3 * 256 + c0);
            edge(jj, x0); edge(jj + 1, x1); edge(jj + 2, x2); edge(jj + 3, x3);
        }
        for (; jj < nb; ++jj) {
            int e0 = __shfl(my_e, jj, 64);
            float4 x0 = *reinterpret_cast<const float4*>(x + (size_t)e0 * 256 + c0);
            edge(jj, x0);
        }
    }
    *reinterpret_cast<float4*>(node_h + (size_t)node * 256 + c0) = make_float4(a0, a1, a2, a3);
}

// ---------------------------------------------------------------------------
// Fused MLP: per block 128 rows, activations stay in LDS (fp32, exact).
//   layer 0: W_up (+b_up, no silu); layers 1-3: Ws (+bs, silu);
//   layer 3 epilogue fuses out = h . W_out  (wave shfl-reduce + LDS atomics)
// A in LDS: [128 rows][64 units of 16B], unit-XOR (r&7) swizzle (2-way = free).
// W frags read directly from L2 (1 MB, shared by all 196 blocks).
// Hi/lo bf16 split on A and W: 3 MFMA terms per k-slice (~fp32 accuracy).
// ---------------------------------------------------------------------------
__global__ __launch_bounds__(512, 1) void mlp_fused(
        const float* __restrict__ node_h,        // [MROWS_PAD][256]
        const unsigned short* __restrict__ W2all,// [4][256][512] hi|lo
        const float* __restrict__ b_up,
        const float* __restrict__ bl,            // [3][256]
        const float* __restrict__ W_out,         // [256]
        float* __restrict__ out, int M) {
    __shared__ float Abuf[32768];                // 128 KiB
    __shared__ float outred[128];
    int tid  = threadIdx.x;
    int row0 = blockIdx.x * 128;
    int wid  = tid >> 6, lane = tid & 63;
    int wm   = (wid >> 2) * 64;
    int wn   = (wid & 3) * 64;
    int fr   = lane & 15, fq = lane >> 4;

    // stage A (fp32) with pre-swizzled source; LDS dest linear (rule #21)
    #pragma unroll
    for (int l = 0; l < 16; ++l) {
        int chunk = l * 512 + tid;               // physical unit index
        int r = chunk >> 6, u = chunk & 63;
        int us = u ^ (r & 7);                    // logical unit at this slot
        gl_lds16(node_h + (size_t)(row0 + r) * 256 + us * 4,
                 ((char*)Abuf) + (size_t)chunk * 16);
    }
    if (tid < 128) outred[tid] = 0.f;
    __syncthreads();

    for (int g = 0; g < 4; ++g) {
        const unsigned short* W2 = W2all + (size_t)g * 131072;
        const float* bias = (g == 0) ? b_up : (bl + (g - 1) * 256);

        f32x4 acc[4][4];
        #pragma unroll
        for (int mi = 0; mi < 4; ++mi)
            #pragma unroll
            for (int nj = 0; nj < 4; ++nj)
                acc[mi][nj] = (f32x4){0.f, 0.f, 0.f, 0.f};

        #pragma unroll
        for (int ks = 0; ks < 8; ++ks) {
            // W frags direct from global (L2-resident)
            frag8 wh[4], wl_[4];
            #pragma unroll
            for (int nj = 0; nj < 4; ++nj) {
                int wrow = wn + nj * 16 + fr;
                const unsigned short* p = W2 + (size_t)wrow * 512 + ks * 32 + fq * 8;
                wh[nj]  = *reinterpret_cast<const frag8*>(p);
                wl_[nj] = *reinterpret_cast<const frag8*>(p + 256);
            }
            // A frags from LDS, split hi/lo on read
            frag8 ah[4], al[4];
            #pragma unroll
            for (int mi = 0; mi < 4; ++mi) {
                int r  = wm + mi * 16 + fr;
                int u0 = ks * 8 + fq * 2;
                const float4 f0 = *reinterpret_cast<const float4*>(
                    Abuf + ((size_t)r * 64 + (u0 ^ (r & 7))) * 4);
                const float4 f1 = *reinterpret_cast<const float4*>(
                    Abuf + ((size_t)r * 64 + ((u0 + 1) ^ (r & 7))) * 4);
                float fv[8] = {f0.x, f0.y, f0.z, f0.w, f1.x, f1.y, f1.z, f1.w};
                #pragma unroll
                for (int j = 0; j < 8; ++j) {
                    short h, l; split2(fv[j], h, l);
                    ah[mi][j] = h; al[mi][j] = l;
                }
            }
            #pragma unroll
            for (int mi = 0; mi < 4; ++mi)
                #pragma unroll
                for (int nj = 0; nj < 4; ++nj) {
                    acc[mi][nj] = __builtin_amdgcn_mfma_f32_16x16x32_bf16(ah[mi], wh[nj],  acc[mi][nj], 0, 0, 0);
                    acc[mi][nj] = __builtin_amdgcn_mfma_f32_16x16x32_bf16(ah[mi], wl_[nj], acc[mi][nj], 0, 0, 0);
                    acc[mi][nj] = __builtin_amdgcn_mfma_f32_16x16x32_bf16(al[mi], wh[nj],  acc[mi][nj], 0, 0, 0);
                }
        }
        __syncthreads();                          // all A reads done

        if (g < 3) {
            float bcol[4];
            #pragma unroll
            for (int nj = 0; nj < 4; ++nj) bcol[nj] = bias[wn + nj * 16 + fr];
            #pragma unroll
            for (int mi = 0; mi < 4; ++mi)
                #pragma unroll
                for (int nj = 0; nj < 4; ++nj)
                    #pragma unroll
                    for (int rr = 0; rr < 4; ++rr) {
                        float v = acc[mi][nj][rr] + bcol[nj];
                        if (g > 0) v = v / (1.f + expf(-v));
                        int row = wm + mi * 16 + fq * 4 + rr;
                        int col = wn + nj * 16 + fr;
                        Abuf[((size_t)row * 64 + ((col >> 2) ^ (row & 7))) * 4 + (col & 3)] = v;
                    }
            __syncthreads();
        } else {
            float bcol[4], wo[4];
            #pragma unroll
            for (int nj = 0; nj < 4; ++nj) {
                int col = wn + nj * 16 + fr;
                bcol[nj] = bias[col]; wo[nj] = W_out[col];
            }
            #pragma unroll
            for (int mi = 0; mi < 4; ++mi)
                #pragma unroll
                for (int rr = 0; rr < 4; ++rr) {
                    float p = 0.f;
                    #pragma unroll
                    for (int nj = 0; nj < 4; ++nj) {
                        float v = acc[mi][nj][rr] + bcol[nj];
                        v = v / (1.f + expf(-v));
                        p += v * wo[nj];
                    }
                    p += __shfl_xor(p, 1, 64);
                    p += __shfl_xor(p, 2, 64);
                    p += __shfl_xor(p, 4, 64);
                    p += __shfl_xor(p, 8, 64);
                    if (fr == 0) atomicAdd(&outred[wm + mi * 16 + fq * 4 + rr], p);
                }
            __syncthreads();
            if (tid < 128) {
                int row = row0 + tid;
                if (row < M) out[row] = outred[tid];
            }
        }
    }
}

// ---------------------------------------------------------------------------
extern "C" void kernel_launch(void* const* d_in, const int* in_sizes, int n_in,
                              void* d_out, int out_size, void* d_ws, size_t ws_size,
                              hipStream_t stream) {
    const float* x     = (const float*)d_in[0];
    const float* rbf   = (const float*)d_in[1];
    const int*   idx   = (const int*)d_in[2];
    const float* W_rbf = (const float*)d_in[4];
    const float* W_up  = (const float*)d_in[5];
    const float* b_up  = (const float*)d_in[6];
    const float* Wl    = (const float*)d_in[7];
    const float* bl    = (const float*)d_in[8];
    const float* W_out = (const float*)d_in[9];
    float* out = (float*)d_out;

    char* ws = (char*)d_ws;
    int*            cnt    = (int*)(ws);
    int*            off    = (int*)(ws + 131072);
    int*            cur    = (int*)(ws + 262144);
    int*            elist  = (int*)(ws + 393216);            // 3.2 MB
    unsigned short* W2all  = (unsigned short*)(ws + 4194304);// 1 MB
    float*          node_h = (float*)(ws + 8388608);         // 25.7 MB

    hipMemsetAsync(cnt, 0, N_NODES * sizeof(int), stream);
    count_kernel<<<(E_EDGES + 255) / 256, 256, 0, stream>>>(idx, cnt);
    scan_kernel<<<1, 1024, 0, stream>>>(cnt, off, cur);
    fill_kernel<<<(E_EDGES + 255) / 256, 256, 0, stream>>>(idx, cur, elist);
    wconv_kernel<<<1024, 256, 0, stream>>>(W_up, Wl, W2all);
    gather_kernel<<<MROWS_PAD, 64, 0, stream>>>(x, rbf, W_rbf, off, cnt, elist, node_h);
    mlp_fused<<<NBLK_M, 512, 0, stream>>>(node_h, W2all, b_up, bl, W_out, out, N_NODES);
}